// Round 8
// baseline (789.432 us; speedup 1.0000x reference)
//
#include <hip/hip_runtime.h>
#include <hip/hip_bf16.h>

#define BB 4
#define TT 2048
#define CC 1024
#define HH 16
#define DD 64
#define BT (BB*TT)   // 8192
#define C3 (3*CC)    // 3072
#define LDST 72      // attn LDS row stride in bf16 elems (144 B)
#define QSCALE 0.18033688011112042f   // 0.125 * log2(e)

typedef __attribute__((ext_vector_type(8))) short short8;
typedef __attribute__((ext_vector_type(4))) float f32x4;

__device__ __forceinline__ short f2bs(float f) {
  __hip_bfloat16 h = __float2bfloat16(f);
  return *reinterpret_cast<short*>(&h);
}

__device__ __forceinline__ void gl_lds16(const short* g, short* l) {
  __builtin_amdgcn_global_load_lds(
      (const __attribute__((address_space(1))) void*)(g),
      (__attribute__((address_space(3))) void*)(l), 16, 0, 0);
}

// ---------------------------------------------------------------------------
// P: single prep launch.
//   blockIdx.x <  48 : Wa [1024][3072] -> Wat [3072][1024] (transpose-cast)
//   blockIdx.x <  64 : Wp [1024][1024] -> Wpt [1024][1024] (transpose-cast)
//   blockIdx.x >= 64 : straight cast x -> Xb (chunk = (x-64)*16 + y)
// ---------------------------------------------------------------------------
__global__ __launch_bounds__(256)
void prep(const float* __restrict__ Wa, short* __restrict__ Wat,
          const float* __restrict__ Wp, short* __restrict__ Wpt,
          const float* __restrict__ x, short* __restrict__ Xb)
{
  __shared__ float Lt[64][65];
  const int bx = blockIdx.x;
  if (bx >= 64) {
    size_t chunk = (size_t)(bx - 64) * 16 + blockIdx.y;
    size_t i = (chunk * 256 + threadIdx.x) * 8;
    float4 a = *reinterpret_cast<const float4*>(x + i);
    float4 b = *reinterpret_cast<const float4*>(x + i + 4);
    short8 o;
    o[0] = f2bs(a.x); o[1] = f2bs(a.y); o[2] = f2bs(a.z); o[3] = f2bs(a.w);
    o[4] = f2bs(b.x); o[5] = f2bs(b.y); o[6] = f2bs(b.z); o[7] = f2bs(b.w);
    *reinterpret_cast<short8*>(Xb + i) = o;
    return;
  }
  const bool isA = (bx < 48);
  const float* in  = isA ? Wa  : Wp;
  short*       out = isA ? Wat : Wpt;
  const int N  = isA ? C3 : CC;
  const int n0 = (isA ? bx : bx - 48) * 64;
  const int k0 = blockIdx.y * 64;
  const int cx = threadIdx.x & 15, rr = threadIdx.x >> 4;
#pragma unroll
  for (int p = 0; p < 4; ++p) {
    int kr = p * 16 + rr;
    float4 u = *reinterpret_cast<const float4*>(in + (size_t)(k0 + kr) * N + n0 + cx * 4);
    Lt[kr][cx * 4 + 0] = u.x;
    Lt[kr][cx * 4 + 1] = u.y;
    Lt[kr][cx * 4 + 2] = u.z;
    Lt[kr][cx * 4 + 3] = u.w;
  }
  __syncthreads();
#pragma unroll
  for (int p = 0; p < 4; ++p) {
    int nr = p * 16 + rr;
    short4 o;
    o.x = f2bs(Lt[cx * 4 + 0][nr]);
    o.y = f2bs(Lt[cx * 4 + 1][nr]);
    o.z = f2bs(Lt[cx * 4 + 2][nr]);
    o.w = f2bs(Lt[cx * 4 + 3][nr]);
    *reinterpret_cast<short4*>(out + (size_t)(n0 + nr) * CC + k0 + cx * 4) = o;
  }
}

// ---------------------------------------------------------------------------
// K1: qkv = Xb @ Wat^T + bias. Verified R6 structure: BK=32, gl_lds x16.
// __launch_bounds__(256,6): VGPR<=85 so all 1536 blocks fit in one
// dispatch round (6 waves/SIMD vs 5 at VGPR=88).
// Epilogue: q bf16 [B,H,T,D] pre-scaled; k bf16 [B,H,T,D]; v bf16 [B,H,D,T]
// with c_s remap baked into t.
// ---------------------------------------------------------------------------
__global__ __launch_bounds__(256, 6)
void qkv_mfma(const short* __restrict__ A, const short* __restrict__ Bt,
              const float* __restrict__ bias,
              short* __restrict__ qb, short* __restrict__ kb, short* __restrict__ vb)
{
  __shared__ __align__(16) short As[128 * 32];
  __shared__ __align__(16) short Bs[128 * 32];
  const int t = threadIdx.x;
  const int lane = t & 63;
  const int l16 = lane & 15, quad = lane >> 4;
  const int w = t >> 6, wm = w & 1, wn = w >> 1;
  const int row0 = blockIdx.y * 128;
  const int col0 = blockIdx.x * 128;

  f32x4 acc[4][4];
#pragma unroll
  for (int i = 0; i < 4; ++i)
#pragma unroll
    for (int j = 0; j < 4; ++j) acc[i][j] = (f32x4){0.f, 0.f, 0.f, 0.f};

  for (int k0 = 0; k0 < CC; k0 += 32) {
    __syncthreads();
#pragma unroll
    for (int p = 0; p < 2; ++p) {
      int idx = p * 256 + t;
      int r = idx >> 2, c = (idx & 3) * 8;
      gl_lds16(A  + (size_t)(row0 + r) * CC + k0 + c, &As[idx * 8]);
      gl_lds16(Bt + (size_t)(col0 + r) * CC + k0 + c, &Bs[idx * 8]);
    }
    __syncthreads();

    short8 af[4], bf[4];
#pragma unroll
    for (int i = 0; i < 4; ++i) {
      af[i] = *reinterpret_cast<const short8*>(&As[(wm * 64 + i * 16 + l16) * 32 + quad * 8]);
      bf[i] = *reinterpret_cast<const short8*>(&Bs[(wn * 64 + i * 16 + l16) * 32 + quad * 8]);
    }
#pragma unroll
    for (int i = 0; i < 4; ++i)
#pragma unroll
      for (int j = 0; j < 4; ++j)
        acc[i][j] = __builtin_amdgcn_mfma_f32_16x16x32_bf16(af[i], bf[j], acc[i][j], 0, 0, 0);
  }

#pragma unroll
  for (int j = 0; j < 4; ++j) {
    int colb = col0 + wn * 64 + j * 16 + l16;
    int sel  = colb >> 10, cin = colb & 1023;
    int h    = cin >> 6,  dd  = cin & 63;
    float bv = bias[colb];
#pragma unroll
    for (int i = 0; i < 4; ++i)
#pragma unroll
      for (int r = 0; r < 4; ++r) {
        int row = row0 + wm * 64 + i * 16 + quad * 4 + r;
        int bi = row >> 11, tt = row & 2047;
        float val = acc[i][j][r] + bv;
        size_t hb = (size_t)(bi * HH + h);
        if (sel == 0) {
          qb[(hb * TT + tt) * DD + dd] = f2bs(val * QSCALE);
        } else if (sel == 1) {
          kb[(hb * TT + tt) * DD + dd] = f2bs(val);
        } else {
          int tp = (tt & ~63) | (((tt & 15) << 2) | ((tt >> 4) & 3));
          vb[(hb * DD + dd) * TT + tp] = f2bs(val);
        }
      }
  }
}

// ---------------------------------------------------------------------------
// K2: MFMA flash attention (verified R6 kernel, unchanged).
// ---------------------------------------------------------------------------
__global__ __launch_bounds__(256, 4)
void attn_mfma(const short* __restrict__ Qb, const short* __restrict__ Kb,
               const short* __restrict__ Vb, short* __restrict__ Y)
{
  __shared__ __align__(16) short Ks[64 * LDST];
  __shared__ __align__(16) short Vt[64 * LDST];
  __shared__ __align__(16) short Pw[4 * 16 * LDST];

  const int t    = threadIdx.x;
  const int w    = t >> 6;
  const int lane = t & 63;
  const int l16  = lane & 15;
  const int quad = lane >> 4;

  const int h  = blockIdx.y, bi = blockIdx.z;
  const size_t head = (size_t)(bi * HH + h) * TT * DD;

  short* myP = &Pw[w * 16 * LDST];
  const int sr = t >> 2;
  const int sc = (t & 3) << 4;

  const int qts[2] = { (int)blockIdx.x, 31 - (int)blockIdx.x };

#pragma unroll
  for (int half = 0; half < 2; ++half) {
    const int qt = qts[half];
    const int q0 = qt * 64;

    short8 qf[2];
#pragma unroll
    for (int kc = 0; kc < 2; ++kc)
      qf[kc] = *reinterpret_cast<const short8*>(
          &Qb[head + (size_t)(q0 + w * 16 + l16) * DD + kc * 32 + quad * 8]);

    f32x4 O[4];
#pragma unroll
    for (int dt = 0; dt < 4; ++dt) O[dt] = (f32x4){0.f, 0.f, 0.f, 0.f};
    float lsum[4] = {};

    for (int kt = 0; kt <= qt; ++kt) {
      const int k0 = kt * 64;
      __syncthreads();

      {
        const short* kg = Kb + head + (size_t)(k0 + sr) * DD + sc;
        short8 a = *reinterpret_cast<const short8*>(kg);
        short8 b = *reinterpret_cast<const short8*>(kg + 8);
        *reinterpret_cast<short8*>(&Ks[sr * LDST + sc])     = a;
        *reinterpret_cast<short8*>(&Ks[sr * LDST + sc + 8]) = b;
        const short* vg = Vb + head + (size_t)sr * TT + k0 + sc;
        short8 c = *reinterpret_cast<const short8*>(vg);
        short8 d = *reinterpret_cast<const short8*>(vg + 8);
        *reinterpret_cast<short8*>(&Vt[sr * LDST + sc])     = c;
        *reinterpret_cast<short8*>(&Vt[sr * LDST + sc + 8]) = d;
      }
      __syncthreads();

      short8 kf[4][2];
#pragma unroll
      for (int nt = 0; nt < 4; ++nt)
#pragma unroll
        for (int kc = 0; kc < 2; ++kc)
          kf[nt][kc] = *reinterpret_cast<const short8*>(
              &Ks[(nt * 16 + l16) * LDST + kc * 32 + quad * 8]);

      f32x4 s[4];
#pragma unroll
      for (int nt = 0; nt < 4; ++nt) s[nt] = (f32x4){0.f, 0.f, 0.f, 0.f};
#pragma unroll
      for (int nt = 0; nt < 4; ++nt)
#pragma unroll
        for (int kc = 0; kc < 2; ++kc)
          s[nt] = __builtin_amdgcn_mfma_f32_16x16x32_bf16(qf[kc], kf[nt][kc], s[nt], 0, 0, 0);

      const int rowg_base = q0 + w * 16 + quad * 4;
#pragma unroll
      for (int r = 0; r < 4; ++r) {
        const int rowg = rowg_base + r;
        short pk[4];
#pragma unroll
        for (int nt = 0; nt < 4; ++nt) {
          float e = (k0 + nt * 16 + l16 <= rowg) ? __builtin_amdgcn_exp2f(s[nt][r]) : 0.f;
          lsum[r] += e;
          pk[nt] = f2bs(e);
        }
        short4 p4; p4.x = pk[0]; p4.y = pk[1]; p4.z = pk[2]; p4.w = pk[3];
        *reinterpret_cast<short4*>(&myP[(quad * 4 + r) * LDST + (l16 << 2)]) = p4;
      }

#pragma unroll
      for (int cc = 0; cc < 2; ++cc) {
        short8 pf = *reinterpret_cast<const short8*>(
            &myP[l16 * LDST + cc * 32 + quad * 8]);
#pragma unroll
        for (int dt = 0; dt < 4; ++dt) {
          short8 vf = *reinterpret_cast<const short8*>(
              &Vt[(dt * 16 + l16) * LDST + cc * 32 + quad * 8]);
          O[dt] = __builtin_amdgcn_mfma_f32_16x16x32_bf16(pf, vf, O[dt], 0, 0, 0);
        }
      }
    }

    float linv[4];
#pragma unroll
    for (int r = 0; r < 4; ++r) {
      float s = lsum[r];
      s += __shfl_xor(s, 1);
      s += __shfl_xor(s, 2);
      s += __shfl_xor(s, 4);
      s += __shfl_xor(s, 8);
      linv[r] = 1.f / s;
    }
#pragma unroll
    for (int dt = 0; dt < 4; ++dt)
#pragma unroll
      for (int r = 0; r < 4; ++r) {
        int tg = q0 + w * 16 + quad * 4 + r;
        Y[((size_t)bi * TT + tg) * CC + h * DD + dt * 16 + l16] =
            f2bs(O[dt][r] * linv[r]);
      }
  }
}

// ---------------------------------------------------------------------------
// K3: out = Yb @ Wpt^T + bias. BK=32 verified structure, launch_bounds(256,6).
// ---------------------------------------------------------------------------
__global__ __launch_bounds__(256, 6)
void proj_mfma(const short* __restrict__ A, const short* __restrict__ Bt,
               const float* __restrict__ bias, float* __restrict__ out)
{
  __shared__ __align__(16) short As[128 * 32];
  __shared__ __align__(16) short Bs[128 * 32];
  const int t = threadIdx.x;
  const int lane = t & 63;
  const int l16 = lane & 15, quad = lane >> 4;
  const int w = t >> 6, wm = w & 1, wn = w >> 1;
  const int row0 = blockIdx.y * 128;
  const int col0 = blockIdx.x * 128;

  f32x4 acc[4][4];
#pragma unroll
  for (int i = 0; i < 4; ++i)
#pragma unroll
    for (int j = 0; j < 4; ++j) acc[i][j] = (f32x4){0.f, 0.f, 0.f, 0.f};

  for (int k0 = 0; k0 < CC; k0 += 32) {
    __syncthreads();
#pragma unroll
    for (int p = 0; p < 2; ++p) {
      int idx = p * 256 + t;
      int r = idx >> 2, c = (idx & 3) * 8;
      gl_lds16(A  + (size_t)(row0 + r) * CC + k0 + c, &As[idx * 8]);
      gl_lds16(Bt + (size_t)(col0 + r) * CC + k0 + c, &Bs[idx * 8]);
    }
    __syncthreads();

    short8 af[4], bf[4];
#pragma unroll
    for (int i = 0; i < 4; ++i) {
      af[i] = *reinterpret_cast<const short8*>(&As[(wm * 64 + i * 16 + l16) * 32 + quad * 8]);
      bf[i] = *reinterpret_cast<const short8*>(&Bs[(wn * 64 + i * 16 + l16) * 32 + quad * 8]);
    }
#pragma unroll
    for (int i = 0; i < 4; ++i)
#pragma unroll
      for (int j = 0; j < 4; ++j)
        acc[i][j] = __builtin_amdgcn_mfma_f32_16x16x32_bf16(af[i], bf[j], acc[i][j], 0, 0, 0);
  }

#pragma unroll
  for (int j = 0; j < 4; ++j) {
    int col = col0 + wn * 64 + j * 16 + l16;
    float bv = bias[col];
#pragma unroll
    for (int i = 0; i < 4; ++i)
#pragma unroll
      for (int r = 0; r < 4; ++r) {
        int row = row0 + wm * 64 + i * 16 + quad * 4 + r;
        out[(size_t)row * CC + col] = acc[i][j][r] + bv;
      }
  }
}

// ---------------------------------------------------------------------------
extern "C" void kernel_launch(void* const* d_in, const int* in_sizes, int n_in,
                              void* d_out, int out_size, void* d_ws, size_t ws_size,
                              hipStream_t stream) {
  const float* x  = (const float*)d_in[0];   // [4,2048,1024] fp32
  const float* Wa = (const float*)d_in[1];   // [1024,3072]  fp32
  const float* ba = (const float*)d_in[2];   // [3072]       fp32
  const float* Wp = (const float*)d_in[3];   // [1024,1024]  fp32
  const float* bp = (const float*)d_in[4];   // [1024]       fp32
  float* out = (float*)d_out;                // [4,2048,1024] fp32

  const size_t NELT = (size_t)BB * HH * TT * DD;   // 8388608
  short* qb  = (short*)d_ws;                       // bf16 [B,H,T,D] (pre-scaled)
  short* kb  = qb + NELT;                          // bf16 [B,H,T,D]
  short* vb  = kb + NELT;                          // bf16 [B,H,D,T] (t remapped)
  short* Xb  = vb + NELT;                          // [8192][1024] bf16
  short* Wat = Xb  + (size_t)BT * CC;              // [3072][1024] bf16 (Wa^T)
  short* Wpt = Wat + (size_t)CC * C3;              // [1024][1024] bf16 (Wp^T)
  short* Yb  = Wpt + (size_t)CC * CC;              // [8192][1024] bf16

  // grid.x: 48 Wa-transpose + 16 Wp-transpose + 256 x-cast columns
  prep<<<dim3(64 + 256, 16), 256, 0, stream>>>(Wa, Wat, Wp, Wpt, x, Xb);

  qkv_mfma <<<dim3(C3 / 128, BT / 128), 256, 0, stream>>>(Xb, Wat, ba, qb, kb, vb);
  attn_mfma<<<dim3(16, HH, BB),         256, 0, stream>>>(qb, kb, vb, Yb);
  proj_mfma<<<dim3(CC / 128, BT / 128), 256, 0, stream>>>(Yb, Wpt, bp, out);
}

// Round 9
// 291.505 us; speedup vs baseline: 2.7081x; 2.7081x over previous
//
#include <hip/hip_runtime.h>
#include <hip/hip_bf16.h>

#define BB 4
#define TT 2048
#define CC 1024
#define HH 16
#define DD 64
#define BT (BB*TT)   // 8192
#define C3 (3*CC)    // 3072
#define LDST 72      // attn LDS row stride in bf16 elems (144 B)
#define QSCALE 0.18033688011112042f   // 0.125 * log2(e)

typedef __attribute__((ext_vector_type(8))) short short8;
typedef __attribute__((ext_vector_type(4))) float f32x4;

__device__ __forceinline__ short f2bs(float f) {
  __hip_bfloat16 h = __float2bfloat16(f);
  return *reinterpret_cast<short*>(&h);
}

__device__ __forceinline__ void gl_lds16(const short* g, short* l) {
  __builtin_amdgcn_global_load_lds(
      (const __attribute__((address_space(1))) void*)(g),
      (__attribute__((address_space(3))) void*)(l), 16, 0, 0);
}

// ---------------------------------------------------------------------------
// P: single prep launch (verified R8).
//   blockIdx.x <  48 : Wa [1024][3072] -> Wat [3072][1024] (transpose-cast)
//   blockIdx.x <  64 : Wp [1024][1024] -> Wpt [1024][1024] (transpose-cast)
//   blockIdx.x >= 64 : straight cast x -> Xb
// ---------------------------------------------------------------------------
__global__ __launch_bounds__(256)
void prep(const float* __restrict__ Wa, short* __restrict__ Wat,
          const float* __restrict__ Wp, short* __restrict__ Wpt,
          const float* __restrict__ x, short* __restrict__ Xb)
{
  __shared__ float Lt[64][65];
  const int bx = blockIdx.x;
  if (bx >= 64) {
    size_t chunk = (size_t)(bx - 64) * 16 + blockIdx.y;
    size_t i = (chunk * 256 + threadIdx.x) * 8;
    float4 a = *reinterpret_cast<const float4*>(x + i);
    float4 b = *reinterpret_cast<const float4*>(x + i + 4);
    short8 o;
    o[0] = f2bs(a.x); o[1] = f2bs(a.y); o[2] = f2bs(a.z); o[3] = f2bs(a.w);
    o[4] = f2bs(b.x); o[5] = f2bs(b.y); o[6] = f2bs(b.z); o[7] = f2bs(b.w);
    *reinterpret_cast<short8*>(Xb + i) = o;
    return;
  }
  const bool isA = (bx < 48);
  const float* in  = isA ? Wa  : Wp;
  short*       out = isA ? Wat : Wpt;
  const int N  = isA ? C3 : CC;
  const int n0 = (isA ? bx : bx - 48) * 64;
  const int k0 = blockIdx.y * 64;
  const int cx = threadIdx.x & 15, rr = threadIdx.x >> 4;
#pragma unroll
  for (int p = 0; p < 4; ++p) {
    int kr = p * 16 + rr;
    float4 u = *reinterpret_cast<const float4*>(in + (size_t)(k0 + kr) * N + n0 + cx * 4);
    Lt[kr][cx * 4 + 0] = u.x;
    Lt[kr][cx * 4 + 1] = u.y;
    Lt[kr][cx * 4 + 2] = u.z;
    Lt[kr][cx * 4 + 3] = u.w;
  }
  __syncthreads();
#pragma unroll
  for (int p = 0; p < 4; ++p) {
    int nr = p * 16 + rr;
    short4 o;
    o.x = f2bs(Lt[cx * 4 + 0][nr]);
    o.y = f2bs(Lt[cx * 4 + 1][nr]);
    o.z = f2bs(Lt[cx * 4 + 2][nr]);
    o.w = f2bs(Lt[cx * 4 + 3][nr]);
    *reinterpret_cast<short4*>(out + (size_t)(n0 + nr) * CC + k0 + cx * 4) = o;
  }
}

// ---------------------------------------------------------------------------
// K1: qkv = Xb @ Wat^T + bias. R6-verified body: BK=32, gl_lds x16.
// __launch_bounds__(256,3): compiler budget is 256 VGPR/SIMD (R8 evidence:
// arg 6 forced VGPR=40=256/6 + spill storm), so arg 3 caps VGPR at 85 —
// which on the 512-reg HW pool gives 6 waves/SIMD = all 1536 blocks in one
// co-residency round. NEVER use arg >=4 here (acc alone is 64 VGPRs).
// ---------------------------------------------------------------------------
__global__ __launch_bounds__(256, 3)
void qkv_mfma(const short* __restrict__ A, const short* __restrict__ Bt,
              const float* __restrict__ bias,
              short* __restrict__ qb, short* __restrict__ kb, short* __restrict__ vb)
{
  __shared__ __align__(16) short As[128 * 32];
  __shared__ __align__(16) short Bs[128 * 32];
  const int t = threadIdx.x;
  const int lane = t & 63;
  const int l16 = lane & 15, quad = lane >> 4;
  const int w = t >> 6, wm = w & 1, wn = w >> 1;
  const int row0 = blockIdx.y * 128;
  const int col0 = blockIdx.x * 128;

  f32x4 acc[4][4];
#pragma unroll
  for (int i = 0; i < 4; ++i)
#pragma unroll
    for (int j = 0; j < 4; ++j) acc[i][j] = (f32x4){0.f, 0.f, 0.f, 0.f};

  for (int k0 = 0; k0 < CC; k0 += 32) {
    __syncthreads();
#pragma unroll
    for (int p = 0; p < 2; ++p) {
      int idx = p * 256 + t;
      int r = idx >> 2, c = (idx & 3) * 8;
      gl_lds16(A  + (size_t)(row0 + r) * CC + k0 + c, &As[idx * 8]);
      gl_lds16(Bt + (size_t)(col0 + r) * CC + k0 + c, &Bs[idx * 8]);
    }
    __syncthreads();

    short8 af[4], bf[4];
#pragma unroll
    for (int i = 0; i < 4; ++i) {
      af[i] = *reinterpret_cast<const short8*>(&As[(wm * 64 + i * 16 + l16) * 32 + quad * 8]);
      bf[i] = *reinterpret_cast<const short8*>(&Bs[(wn * 64 + i * 16 + l16) * 32 + quad * 8]);
    }
#pragma unroll
    for (int i = 0; i < 4; ++i)
#pragma unroll
      for (int j = 0; j < 4; ++j)
        acc[i][j] = __builtin_amdgcn_mfma_f32_16x16x32_bf16(af[i], bf[j], acc[i][j], 0, 0, 0);
  }

#pragma unroll
  for (int j = 0; j < 4; ++j) {
    int colb = col0 + wn * 64 + j * 16 + l16;
    int sel  = colb >> 10, cin = colb & 1023;
    int h    = cin >> 6,  dd  = cin & 63;
    float bv = bias[colb];
#pragma unroll
    for (int i = 0; i < 4; ++i)
#pragma unroll
      for (int r = 0; r < 4; ++r) {
        int row = row0 + wm * 64 + i * 16 + quad * 4 + r;
        int bi = row >> 11, tt = row & 2047;
        float val = acc[i][j][r] + bv;
        size_t hb = (size_t)(bi * HH + h);
        if (sel == 0) {
          qb[(hb * TT + tt) * DD + dd] = f2bs(val * QSCALE);
        } else if (sel == 1) {
          kb[(hb * TT + tt) * DD + dd] = f2bs(val);
        } else {
          int tp = (tt & ~63) | (((tt & 15) << 2) | ((tt >> 4) & 3));
          vb[(hb * DD + dd) * TT + tp] = f2bs(val);
        }
      }
  }
}

// ---------------------------------------------------------------------------
// K2: MFMA flash attention (verified R6 kernel, unchanged).
// ---------------------------------------------------------------------------
__global__ __launch_bounds__(256, 4)
void attn_mfma(const short* __restrict__ Qb, const short* __restrict__ Kb,
               const short* __restrict__ Vb, short* __restrict__ Y)
{
  __shared__ __align__(16) short Ks[64 * LDST];
  __shared__ __align__(16) short Vt[64 * LDST];
  __shared__ __align__(16) short Pw[4 * 16 * LDST];

  const int t    = threadIdx.x;
  const int w    = t >> 6;
  const int lane = t & 63;
  const int l16  = lane & 15;
  const int quad = lane >> 4;

  const int h  = blockIdx.y, bi = blockIdx.z;
  const size_t head = (size_t)(bi * HH + h) * TT * DD;

  short* myP = &Pw[w * 16 * LDST];
  const int sr = t >> 2;
  const int sc = (t & 3) << 4;

  const int qts[2] = { (int)blockIdx.x, 31 - (int)blockIdx.x };

#pragma unroll
  for (int half = 0; half < 2; ++half) {
    const int qt = qts[half];
    const int q0 = qt * 64;

    short8 qf[2];
#pragma unroll
    for (int kc = 0; kc < 2; ++kc)
      qf[kc] = *reinterpret_cast<const short8*>(
          &Qb[head + (size_t)(q0 + w * 16 + l16) * DD + kc * 32 + quad * 8]);

    f32x4 O[4];
#pragma unroll
    for (int dt = 0; dt < 4; ++dt) O[dt] = (f32x4){0.f, 0.f, 0.f, 0.f};
    float lsum[4] = {};

    for (int kt = 0; kt <= qt; ++kt) {
      const int k0 = kt * 64;
      __syncthreads();

      {
        const short* kg = Kb + head + (size_t)(k0 + sr) * DD + sc;
        short8 a = *reinterpret_cast<const short8*>(kg);
        short8 b = *reinterpret_cast<const short8*>(kg + 8);
        *reinterpret_cast<short8*>(&Ks[sr * LDST + sc])     = a;
        *reinterpret_cast<short8*>(&Ks[sr * LDST + sc + 8]) = b;
        const short* vg = Vb + head + (size_t)sr * TT + k0 + sc;
        short8 c = *reinterpret_cast<const short8*>(vg);
        short8 d = *reinterpret_cast<const short8*>(vg + 8);
        *reinterpret_cast<short8*>(&Vt[sr * LDST + sc])     = c;
        *reinterpret_cast<short8*>(&Vt[sr * LDST + sc + 8]) = d;
      }
      __syncthreads();

      short8 kf[4][2];
#pragma unroll
      for (int nt = 0; nt < 4; ++nt)
#pragma unroll
        for (int kc = 0; kc < 2; ++kc)
          kf[nt][kc] = *reinterpret_cast<const short8*>(
              &Ks[(nt * 16 + l16) * LDST + kc * 32 + quad * 8]);

      f32x4 s[4];
#pragma unroll
      for (int nt = 0; nt < 4; ++nt) s[nt] = (f32x4){0.f, 0.f, 0.f, 0.f};
#pragma unroll
      for (int nt = 0; nt < 4; ++nt)
#pragma unroll
        for (int kc = 0; kc < 2; ++kc)
          s[nt] = __builtin_amdgcn_mfma_f32_16x16x32_bf16(qf[kc], kf[nt][kc], s[nt], 0, 0, 0);

      const int rowg_base = q0 + w * 16 + quad * 4;
#pragma unroll
      for (int r = 0; r < 4; ++r) {
        const int rowg = rowg_base + r;
        short pk[4];
#pragma unroll
        for (int nt = 0; nt < 4; ++nt) {
          float e = (k0 + nt * 16 + l16 <= rowg) ? __builtin_amdgcn_exp2f(s[nt][r]) : 0.f;
          lsum[r] += e;
          pk[nt] = f2bs(e);
        }
        short4 p4; p4.x = pk[0]; p4.y = pk[1]; p4.z = pk[2]; p4.w = pk[3];
        *reinterpret_cast<short4*>(&myP[(quad * 4 + r) * LDST + (l16 << 2)]) = p4;
      }

#pragma unroll
      for (int cc = 0; cc < 2; ++cc) {
        short8 pf = *reinterpret_cast<const short8*>(
            &myP[l16 * LDST + cc * 32 + quad * 8]);
#pragma unroll
        for (int dt = 0; dt < 4; ++dt) {
          short8 vf = *reinterpret_cast<const short8*>(
              &Vt[(dt * 16 + l16) * LDST + cc * 32 + quad * 8]);
          O[dt] = __builtin_amdgcn_mfma_f32_16x16x32_bf16(pf, vf, O[dt], 0, 0, 0);
        }
      }
    }

    float linv[4];
#pragma unroll
    for (int r = 0; r < 4; ++r) {
      float s = lsum[r];
      s += __shfl_xor(s, 1);
      s += __shfl_xor(s, 2);
      s += __shfl_xor(s, 4);
      s += __shfl_xor(s, 8);
      linv[r] = 1.f / s;
    }
#pragma unroll
    for (int dt = 0; dt < 4; ++dt)
#pragma unroll
      for (int r = 0; r < 4; ++r) {
        int tg = q0 + w * 16 + quad * 4 + r;
        Y[((size_t)bi * TT + tg) * CC + h * DD + dt * 16 + l16] =
            f2bs(O[dt][r] * linv[r]);
      }
  }
}

// ---------------------------------------------------------------------------
// K3: out = Yb @ Wpt^T + bias. R6-verified body, launch_bounds(256,3).
// ---------------------------------------------------------------------------
__global__ __launch_bounds__(256, 3)
void proj_mfma(const short* __restrict__ A, const short* __restrict__ Bt,
               const float* __restrict__ bias, float* __restrict__ out)
{
  __shared__ __align__(16) short As[128 * 32];
  __shared__ __align__(16) short Bs[128 * 32];
  const int t = threadIdx.x;
  const int lane = t & 63;
  const int l16 = lane & 15, quad = lane >> 4;
  const int w = t >> 6, wm = w & 1, wn = w >> 1;
  const int row0 = blockIdx.y * 128;
  const int col0 = blockIdx.x * 128;

  f32x4 acc[4][4];
#pragma unroll
  for (int i = 0; i < 4; ++i)
#pragma unroll
    for (int j = 0; j < 4; ++j) acc[i][j] = (f32x4){0.f, 0.f, 0.f, 0.f};

  for (int k0 = 0; k0 < CC; k0 += 32) {
    __syncthreads();
#pragma unroll
    for (int p = 0; p < 2; ++p) {
      int idx = p * 256 + t;
      int r = idx >> 2, c = (idx & 3) * 8;
      gl_lds16(A  + (size_t)(row0 + r) * CC + k0 + c, &As[idx * 8]);
      gl_lds16(Bt + (size_t)(col0 + r) * CC + k0 + c, &Bs[idx * 8]);
    }
    __syncthreads();

    short8 af[4], bf[4];
#pragma unroll
    for (int i = 0; i < 4; ++i) {
      af[i] = *reinterpret_cast<const short8*>(&As[(wm * 64 + i * 16 + l16) * 32 + quad * 8]);
      bf[i] = *reinterpret_cast<const short8*>(&Bs[(wn * 64 + i * 16 + l16) * 32 + quad * 8]);
    }
#pragma unroll
    for (int i = 0; i < 4; ++i)
#pragma unroll
      for (int j = 0; j < 4; ++j)
        acc[i][j] = __builtin_amdgcn_mfma_f32_16x16x32_bf16(af[i], bf[j], acc[i][j], 0, 0, 0);
  }

#pragma unroll
  for (int j = 0; j < 4; ++j) {
    int col = col0 + wn * 64 + j * 16 + l16;
    float bv = bias[col];
#pragma unroll
    for (int i = 0; i < 4; ++i)
#pragma unroll
      for (int r = 0; r < 4; ++r) {
        int row = row0 + wm * 64 + i * 16 + quad * 4 + r;
        out[(size_t)row * CC + col] = acc[i][j][r] + bv;
      }
  }
}

// ---------------------------------------------------------------------------
extern "C" void kernel_launch(void* const* d_in, const int* in_sizes, int n_in,
                              void* d_out, int out_size, void* d_ws, size_t ws_size,
                              hipStream_t stream) {
  const float* x  = (const float*)d_in[0];   // [4,2048,1024] fp32
  const float* Wa = (const float*)d_in[1];   // [1024,3072]  fp32
  const float* ba = (const float*)d_in[2];   // [3072]       fp32
  const float* Wp = (const float*)d_in[3];   // [1024,1024]  fp32
  const float* bp = (const float*)d_in[4];   // [1024]       fp32
  float* out = (float*)d_out;                // [4,2048,1024] fp32

  const size_t NELT = (size_t)BB * HH * TT * DD;   // 8388608
  short* qb  = (short*)d_ws;                       // bf16 [B,H,T,D] (pre-scaled)
  short* kb  = qb + NELT;                          // bf16 [B,H,T,D]
  short* vb  = kb + NELT;                          // bf16 [B,H,D,T] (t remapped)
  short* Xb  = vb + NELT;                          // [8192][1024] bf16
  short* Wat = Xb  + (size_t)BT * CC;              // [3072][1024] bf16 (Wa^T)
  short* Wpt = Wat + (size_t)CC * C3;              // [1024][1024] bf16 (Wp^T)
  short* Yb  = Wpt + (size_t)CC * CC;              // [8192][1024] bf16

  prep<<<dim3(64 + 256, 16), 256, 0, stream>>>(Wa, Wat, Wp, Wpt, x, Xb);

  qkv_mfma <<<dim3(C3 / 128, BT / 128), 256, 0, stream>>>(Xb, Wat, ba, qb, kb, vb);
  attn_mfma<<<dim3(16, HH, BB),         256, 0, stream>>>(qb, kb, vb, Yb);
  proj_mfma<<<dim3(CC / 128, BT / 128), 256, 0, stream>>>(Yb, Wpt, bp, out);
}